// Round 10
// baseline (230.278 us; speedup 1.0000x reference)
//
#include <hip/hip_runtime.h>

#define N_NODES  100000
#define N_EDGES  1600000
#define N_GRAPHS 256
#define F        64

#define BSHIFT   8
#define BNODES   256                          // nodes per bucket
#define NBUCKET  391                          // ceil(N_NODES / 256)
#define CHUNK    8192
#define NCHUNK   196                          // ceil(N_EDGES / CHUNK)

// ---------- K1: per-chunk bucket histogram (LDS atomics only) ----------
__global__ __launch_bounds__(1024) void hist_kernel(
        const int* __restrict__ dst, int* __restrict__ cnt) {
    __shared__ int hist[NBUCKET];
    int tid = threadIdx.x;
    for (int b = tid; b < NBUCKET; b += 1024) hist[b] = 0;
    __syncthreads();
    int base = blockIdx.x * CHUNK;
    int end  = min(base + CHUNK, N_EDGES);
    for (int e = base + tid; e < end; e += 1024)
        atomicAdd(&hist[dst[e] >> BSHIFT], 1);
    __syncthreads();
    for (int b = tid; b < NBUCKET; b += 1024)
        cnt[blockIdx.x * NBUCKET + b] = hist[b];
}

// ---------- K2: global slot starts per (chunk,bucket) + bucket bases ----------
__global__ __launch_bounds__(512) void chunk_scan_kernel(
        const int* __restrict__ cnt, int* __restrict__ start, int* __restrict__ bbase) {
    __shared__ int t[512];
    int b = threadIdx.x;
    int tot = 0;
    if (b < NBUCKET)
        for (int c = 0; c < NCHUNK; ++c) tot += cnt[c * NBUCKET + b];  // coalesced
    t[b] = (b < NBUCKET) ? tot : 0;
    __syncthreads();
    #pragma unroll
    for (int o = 1; o < 512; o <<= 1) {           // inclusive scan
        int u = (b >= o) ? t[b - o] : 0;
        __syncthreads();
        t[b] += u;
        __syncthreads();
    }
    if (b < NBUCKET) {
        int base = t[b] - tot;                    // exclusive
        bbase[b] = base;
        if (b == NBUCKET - 1) bbase[NBUCKET] = t[b];
        int run = base;
        for (int c = 0; c < NCHUNK; ++c) {
            start[c * NBUCKET + b] = run;         // coalesced
            run += cnt[c * NBUCKET + b];
        }
    }
}

// ---------- K3: bucket-partitioned scatter of packed (dstLocal<<17 | src) ----------
__global__ __launch_bounds__(1024) void scatter_kernel(
        const int* __restrict__ src, const int* __restrict__ dst,
        const int* __restrict__ start, unsigned int* __restrict__ pairs) {
    __shared__ int cur[NBUCKET];
    int tid = threadIdx.x;
    for (int b = tid; b < NBUCKET; b += 1024)
        cur[b] = start[blockIdx.x * NBUCKET + b];
    __syncthreads();
    int base = blockIdx.x * CHUNK;
    int end  = min(base + CHUNK, N_EDGES);
    for (int e = base + tid; e < end; e += 1024) {
        int d = dst[e];
        int slot = atomicAdd(&cur[d >> BSHIFT], 1);
        pairs[slot] = ((unsigned)(d & (BNODES - 1)) << 17) | (unsigned)src[e];
    }
}

// ---------- K4: per-bucket counting sort -> CSR (eidx sorted by dst, noff) ----------
__global__ __launch_bounds__(1024) void bucket_sort_kernel(
        const unsigned int* __restrict__ pairs,
        const int* __restrict__ bbase,
        int* __restrict__ eidx, int* __restrict__ noff) {
    __shared__ int cnt[BNODES];
    __shared__ int pref[BNODES];
    __shared__ int cur[BNODES];
    int tid = threadIdx.x;
    int b = blockIdx.x;
    int lo = bbase[b], hi = bbase[b + 1];

    if (tid < BNODES) cnt[tid] = 0;
    __syncthreads();
    for (int e = lo + tid; e < hi; e += 1024)
        atomicAdd(&cnt[pairs[e] >> 17], 1);
    __syncthreads();
    if (tid < BNODES) pref[tid] = cnt[tid];
    __syncthreads();
    #pragma unroll
    for (int o = 1; o < BNODES; o <<= 1) {
        int u = (tid < BNODES && tid >= o) ? pref[tid - o] : 0;
        __syncthreads();
        if (tid < BNODES) pref[tid] += u;
        __syncthreads();
    }
    if (tid < BNODES) {
        int excl = lo + pref[tid] - cnt[tid];
        cur[tid] = excl;
        int node = b * BNODES + tid;
        if (node < N_NODES) noff[node] = excl;
        if (node == N_NODES - 1) noff[N_NODES] = hi;
    }
    __syncthreads();
    for (int e = lo + tid; e < hi; e += 1024) {
        unsigned int p = pairs[e];
        int slot = atomicAdd(&cur[p >> 17], 1);
        eidx[slot] = (int)(p & 0x1FFFFu);   // writes stay in a 16KB L2-resident window
    }
}

// ---------- K5: fused gather + transform + attention pool ----------
// Wave-per-13-node-chunk (7693 waves -> ~30 resident waves/CU; R8's 25-node
// version was grid-limited to ~16 waves/CU). R6-proven gather + readlane
// matmul; unshifted-exp softmax accumulated in registers, atomic flush at
// graph boundaries only.
#define NODES_PER_WAVE 13
#define GT_NWAVES  ((N_NODES + NODES_PER_WAVE - 1) / NODES_PER_WAVE)  // 7693
#define GT_BLOCKS  ((GT_NWAVES + 3) / 4)                              // 1924

__global__ __launch_bounds__(256, 4) void gather_pool_kernel(
        const float* __restrict__ x,
        const int*   __restrict__ noff,
        const int*   __restrict__ eidx,
        const int*   __restrict__ batch,
        const float* __restrict__ Wg,   // [64,64] (k, f)
        const float* __restrict__ bg,
        const float* __restrict__ Wa,
        const float* __restrict__ ba,
        float*       __restrict__ out_acc,   // [N_GRAPHS, F] accumulated
        float*       __restrict__ denom) {   // [N_GRAPHS]
    int tid  = threadIdx.x;
    int lane = tid & 63;
    int grp  = lane >> 4;   // 0..3: row within a 4-row gather batch
    int c    = lane & 15;   // float4 chunk within a row
    int waveId = blockIdx.x * 4 + (tid >> 6);

    int n0 = waveId * NODES_PER_WAVE;
    if (n0 >= N_NODES) return;
    int nEnd = n0 + NODES_PER_WAVE;
    if (nEnd > N_NODES) nEnd = N_NODES;

    float wcol[F];
    #pragma unroll
    for (int k = 0; k < F; ++k) wcol[k] = Wg[k * F + lane];
    float bgl = bg[lane];
    float wal = Wa[lane];
    float ba0 = ba[0];

    const float4* x4 = (const float4*)x;

    int   cur_g = batch[n0];
    float accw  = 0.f;   // per-lane: sum e * h[lane]
    float denw  = 0.f;   // replicated: sum e

    for (int n = n0; n < nEnd; ++n) {
        int start = noff[n];
        int end   = noff[n + 1];

        float4 a = make_float4(0.f, 0.f, 0.f, 0.f);
        for (int base = start; base < end; base += 64) {
            int jmax = end - base; if (jmax > 64) jmax = 64;
            int sl = (base + lane < end) ? eidx[base + lane] : 0;   // coalesced
            for (int j = 0; j < jmax; j += 4) {
                int el = j + grp;
                int s  = __shfl(sl, el, 64);
                if (el < jmax) {
                    float4 v = x4[s * 16 + c];   // 4 rows / wave-instruction
                    a.x += v.x; a.y += v.y; a.z += v.z; a.w += v.w;
                }
            }
        }
        #pragma unroll
        for (int o = 16; o <= 32; o <<= 1) {
            a.x += __shfl_xor(a.x, o, 64);
            a.y += __shfl_xor(a.y, o, 64);
            a.z += __shfl_xor(a.z, o, 64);
            a.w += __shfl_xor(a.w, o, 64);
        }
        { float4 v = x4[n * 16 + c]; a.x += v.x; a.y += v.y; a.z += v.z; a.w += v.w; }

        float re[4] = {a.x, a.y, a.z, a.w};
        float acc0 = 0.f, acc1 = 0.f, acc2 = 0.f, acc3 = 0.f;
        #pragma unroll
        for (int k = 0; k < F; k += 4) {
            float r0 = __int_as_float(__builtin_amdgcn_readlane(__float_as_int(re[0]), k >> 2));
            float r1 = __int_as_float(__builtin_amdgcn_readlane(__float_as_int(re[1]), k >> 2));
            float r2 = __int_as_float(__builtin_amdgcn_readlane(__float_as_int(re[2]), k >> 2));
            float r3 = __int_as_float(__builtin_amdgcn_readlane(__float_as_int(re[3]), k >> 2));
            acc0 += r0 * wcol[k + 0];
            acc1 += r1 * wcol[k + 1];
            acc2 += r2 * wcol[k + 2];
            acc3 += r3 * wcol[k + 3];
        }
        float hv = (acc0 + acc1) + (acc2 + acc3) + bgl;
        hv = hv > 0.f ? hv : 0.f;

        float p = hv * wal;
        #pragma unroll
        for (int o = 32; o > 0; o >>= 1)
            p += __shfl_down(p, o, 64);
        float s = __int_as_float(__builtin_amdgcn_readlane(__float_as_int(p), 0)) + ba0;
        float e = __expf(s);    // unshifted: softmax ratio is shift-invariant

        int g = batch[n];       // wave-uniform
        if (g != cur_g) {
            atomicAdd(&out_acc[cur_g * F + lane], accw);
            if (lane == 0) atomicAdd(&denom[cur_g], denw);
            accw = 0.f; denw = 0.f; cur_g = g;
        }
        accw += e * hv;
        denw += e;
    }
    atomicAdd(&out_acc[cur_g * F + lane], accw);
    if (lane == 0) atomicAdd(&denom[cur_g], denw);
}

// ---------- K6: out /= denom ----------
__global__ __launch_bounds__(256) void finalize_kernel(
        float* __restrict__ out, const float* __restrict__ denom) {
    int i = blockIdx.x * 256 + threadIdx.x;
    if (i >= N_GRAPHS * F) return;
    float d = denom[i >> 6];
    out[i] = (d > 0.f) ? out[i] / d : 0.f;
}

extern "C" void kernel_launch(void* const* d_in, const int* in_sizes, int n_in,
                              void* d_out, int out_size, void* d_ws, size_t ws_size,
                              hipStream_t stream) {
    const float* x     = (const float*)d_in[0];
    const int*   ei    = (const int*)d_in[1];   // [2, N_EDGES]
    const int*   batch = (const int*)d_in[2];   // [N_NODES]
    const float* Wg    = (const float*)d_in[3];
    const float* bg    = (const float*)d_in[4];
    const float* Wa    = (const float*)d_in[5];
    const float* ba    = (const float*)d_in[6];
    float* out = (float*)d_out;

    const int* src = ei;
    const int* dst = ei + N_EDGES;

    // workspace layout (bytes, 256-aligned)
    char* ws = (char*)d_ws;
    int*          cnt    = (int*)(ws);                     // 306,544
    int*          start  = (int*)(ws +   306688);          // 306,544
    int*          bbase  = (int*)(ws +   613376);          // 1,568
    unsigned int* pairs  = (unsigned int*)(ws +  615168);  // 6,400,000
    int*          eidx   = (int*)(ws +  7015168);          // 6,400,000
    int*          noff   = (int*)(ws + 13415168);          // 400,004
    float*        denom  = (float*)(ws + 13815424);        // 1,024

    hipMemsetAsync(out,   0, (size_t)N_GRAPHS * F * sizeof(float), stream);
    hipMemsetAsync(denom, 0, N_GRAPHS * sizeof(float), stream);

    hist_kernel        <<<NCHUNK, 1024, 0, stream>>>(dst, cnt);
    chunk_scan_kernel  <<<1, 512, 0, stream>>>(cnt, start, bbase);
    scatter_kernel     <<<NCHUNK, 1024, 0, stream>>>(src, dst, start, pairs);
    bucket_sort_kernel <<<NBUCKET, 1024, 0, stream>>>(pairs, bbase, eidx, noff);
    gather_pool_kernel <<<GT_BLOCKS, 256, 0, stream>>>(
        x, noff, eidx, batch, Wg, bg, Wa, ba, out, denom);
    finalize_kernel    <<<(N_GRAPHS * F + 255) / 256, 256, 0, stream>>>(out, denom);
}

// Round 11
// 217.998 us; speedup vs baseline: 1.0563x; 1.0563x over previous
//
#include <hip/hip_runtime.h>

#define N_NODES  100000
#define N_EDGES  1600000
#define N_GRAPHS 256
#define F        64

#define BSHIFT   8
#define BNODES   256                          // nodes per bucket
#define NBUCKET  391                          // ceil(N_NODES / 256)
#define CHUNK    8192
#define NCHUNK   196                          // ceil(N_EDGES / CHUNK)

// ---------- K0: cast x (fp32) -> xh (bf16, RNE) ----------
__device__ __forceinline__ unsigned short f2bf(float f) {
    unsigned int u = __float_as_uint(f);
    u += 0x7FFFu + ((u >> 16) & 1u);
    return (unsigned short)(u >> 16);
}
__global__ __launch_bounds__(256) void cast_kernel(
        const float* __restrict__ x, unsigned short* __restrict__ xh) {
    int i = blockIdx.x * 256 + threadIdx.x;            // one float4 per thread
    float4 v = ((const float4*)x)[i];                  // N_NODES*F/4 = 1.6M threads
    ushort4 o;
    o.x = f2bf(v.x); o.y = f2bf(v.y); o.z = f2bf(v.z); o.w = f2bf(v.w);
    ((ushort4*)xh)[i] = o;
}

// ---------- K1: per-chunk bucket histogram (LDS atomics only) ----------
__global__ __launch_bounds__(1024) void hist_kernel(
        const int* __restrict__ dst, int* __restrict__ cnt) {
    __shared__ int hist[NBUCKET];
    int tid = threadIdx.x;
    for (int b = tid; b < NBUCKET; b += 1024) hist[b] = 0;
    __syncthreads();
    int base = blockIdx.x * CHUNK;
    int end  = min(base + CHUNK, N_EDGES);
    for (int e = base + tid; e < end; e += 1024)
        atomicAdd(&hist[dst[e] >> BSHIFT], 1);
    __syncthreads();
    for (int b = tid; b < NBUCKET; b += 1024)
        cnt[blockIdx.x * NBUCKET + b] = hist[b];
}

// ---------- K2: global slot starts per (chunk,bucket) + bucket bases ----------
__global__ __launch_bounds__(512) void chunk_scan_kernel(
        const int* __restrict__ cnt, int* __restrict__ start, int* __restrict__ bbase) {
    __shared__ int t[512];
    int b = threadIdx.x;
    int tot = 0;
    if (b < NBUCKET)
        for (int c = 0; c < NCHUNK; ++c) tot += cnt[c * NBUCKET + b];  // coalesced
    t[b] = (b < NBUCKET) ? tot : 0;
    __syncthreads();
    #pragma unroll
    for (int o = 1; o < 512; o <<= 1) {           // inclusive scan
        int u = (b >= o) ? t[b - o] : 0;
        __syncthreads();
        t[b] += u;
        __syncthreads();
    }
    if (b < NBUCKET) {
        int base = t[b] - tot;                    // exclusive
        bbase[b] = base;
        if (b == NBUCKET - 1) bbase[NBUCKET] = t[b];
        int run = base;
        for (int c = 0; c < NCHUNK; ++c) {
            start[c * NBUCKET + b] = run;         // coalesced
            run += cnt[c * NBUCKET + b];
        }
    }
}

// ---------- K3: bucket-partitioned scatter of packed (dstLocal<<17 | src) ----------
__global__ __launch_bounds__(1024) void scatter_kernel(
        const int* __restrict__ src, const int* __restrict__ dst,
        const int* __restrict__ start, unsigned int* __restrict__ pairs) {
    __shared__ int cur[NBUCKET];
    int tid = threadIdx.x;
    for (int b = tid; b < NBUCKET; b += 1024)
        cur[b] = start[blockIdx.x * NBUCKET + b];
    __syncthreads();
    int base = blockIdx.x * CHUNK;
    int end  = min(base + CHUNK, N_EDGES);
    for (int e = base + tid; e < end; e += 1024) {
        int d = dst[e];
        int slot = atomicAdd(&cur[d >> BSHIFT], 1);
        pairs[slot] = ((unsigned)(d & (BNODES - 1)) << 17) | (unsigned)src[e];
    }
}

// ---------- K4: per-bucket counting sort -> CSR (eidx sorted by dst, noff) ----------
__global__ __launch_bounds__(1024) void bucket_sort_kernel(
        const unsigned int* __restrict__ pairs,
        const int* __restrict__ bbase,
        int* __restrict__ eidx, int* __restrict__ noff) {
    __shared__ int cnt[BNODES];
    __shared__ int pref[BNODES];
    __shared__ int cur[BNODES];
    int tid = threadIdx.x;
    int b = blockIdx.x;
    int lo = bbase[b], hi = bbase[b + 1];

    if (tid < BNODES) cnt[tid] = 0;
    __syncthreads();
    for (int e = lo + tid; e < hi; e += 1024)
        atomicAdd(&cnt[pairs[e] >> 17], 1);
    __syncthreads();
    if (tid < BNODES) pref[tid] = cnt[tid];
    __syncthreads();
    #pragma unroll
    for (int o = 1; o < BNODES; o <<= 1) {
        int u = (tid < BNODES && tid >= o) ? pref[tid - o] : 0;
        __syncthreads();
        if (tid < BNODES) pref[tid] += u;
        __syncthreads();
    }
    if (tid < BNODES) {
        int excl = lo + pref[tid] - cnt[tid];
        cur[tid] = excl;
        int node = b * BNODES + tid;
        if (node < N_NODES) noff[node] = excl;
        if (node == N_NODES - 1) noff[N_NODES] = hi;
    }
    __syncthreads();
    for (int e = lo + tid; e < hi; e += 1024) {
        unsigned int p = pairs[e];
        int slot = atomicAdd(&cur[p >> 17], 1);
        eidx[slot] = (int)(p & 0x1FFFFu);   // writes stay in a 16KB L2-resident window
    }
}

// ---------- K5: fused gather(bf16) + transform + attention pool ----------
// bf16 rows are 128 B: 8 lanes x 16 B per row -> 8 rows per wave-instruction.
// Wave-per-25-node-chunk (R8-proven); no waves/EU pin so wcol[64] can live in
// registers. Unshifted-exp softmax accumulated in registers, atomic flush at
// graph boundaries only.
#define NODES_PER_WAVE 25
#define GT_NWAVES  (N_NODES / NODES_PER_WAVE)   // 4000
#define GT_BLOCKS  (GT_NWAVES / 4)              // 1000

__device__ __forceinline__ float bfl(unsigned int u) {   // low bf16 -> f32
    return __uint_as_float(u << 16);
}
__device__ __forceinline__ float bfh(unsigned int u) {   // high bf16 -> f32
    return __uint_as_float(u & 0xFFFF0000u);
}

__global__ __launch_bounds__(256) void gather_pool_kernel(
        const unsigned short* __restrict__ xh,
        const int*   __restrict__ noff,
        const int*   __restrict__ eidx,
        const int*   __restrict__ batch,
        const float* __restrict__ Wg,   // [64,64] (k, f)
        const float* __restrict__ bg,
        const float* __restrict__ Wa,
        const float* __restrict__ ba,
        float*       __restrict__ out_acc,   // [N_GRAPHS, F] accumulated
        float*       __restrict__ denom) {   // [N_GRAPHS]
    int tid  = threadIdx.x;
    int lane = tid & 63;
    int grp  = lane >> 3;   // 0..7: row within an 8-row gather batch
    int c    = lane & 7;    // 16-B chunk (8 bf16) within a row
    int waveId = blockIdx.x * 4 + (tid >> 6);

    int n0 = waveId * NODES_PER_WAVE;
    if (n0 >= N_NODES) return;
    int nEnd = n0 + NODES_PER_WAVE;          // N_NODES % 25 == 0

    float wcol[F];
    #pragma unroll
    for (int k = 0; k < F; ++k) wcol[k] = Wg[k * F + lane];
    float bgl = bg[lane];
    float wal = Wa[lane];
    float ba0 = ba[0];

    const uint4* xh4 = (const uint4*)xh;     // row = 8 uint4

    int   cur_g = batch[n0];
    float accw  = 0.f;   // per-lane: sum e * h[lane]
    float denw  = 0.f;   // replicated: sum e

    for (int n = n0; n < nEnd; ++n) {
        int start = noff[n];
        int end   = noff[n + 1];

        float a0=0.f,a1=0.f,a2=0.f,a3=0.f,a4=0.f,a5=0.f,a6=0.f,a7=0.f;
        for (int base = start; base < end; base += 64) {
            int jmax = end - base; if (jmax > 64) jmax = 64;
            int sl = (base + lane < end) ? eidx[base + lane] : 0;   // coalesced
            for (int j = 0; j < jmax; j += 8) {
                int el = j + grp;
                int s  = __shfl(sl, el, 64);
                if (el < jmax) {
                    uint4 v = xh4[s * 8 + c];   // 16 B/lane, 8 rows per instruction
                    a0 += bfl(v.x); a1 += bfh(v.x);
                    a2 += bfl(v.y); a3 += bfh(v.y);
                    a4 += bfl(v.z); a5 += bfh(v.z);
                    a6 += bfl(v.w); a7 += bfh(v.w);
                }
            }
        }
        // combine the 8 group-partials (xor 8,16,32): all lanes get full chunk sums
        #pragma unroll
        for (int o = 8; o <= 32; o <<= 1) {
            a0 += __shfl_xor(a0, o, 64); a1 += __shfl_xor(a1, o, 64);
            a2 += __shfl_xor(a2, o, 64); a3 += __shfl_xor(a3, o, 64);
            a4 += __shfl_xor(a4, o, 64); a5 += __shfl_xor(a5, o, 64);
            a6 += __shfl_xor(a6, o, 64); a7 += __shfl_xor(a7, o, 64);
        }
        // add self row once (every lane holds its chunk of the complete row)
        {
            uint4 v = xh4[n * 8 + c];
            a0 += bfl(v.x); a1 += bfh(v.x);
            a2 += bfl(v.y); a3 += bfh(v.y);
            a4 += bfl(v.z); a5 += bfh(v.z);
            a6 += bfl(v.w); a7 += bfh(v.w);
        }

        // matmul: row element k lives at lane k>>3 (lanes 0..7), slot k&7
        float re[8] = {a0,a1,a2,a3,a4,a5,a6,a7};
        float q0=0.f,q1=0.f,q2=0.f,q3=0.f,q4=0.f,q5=0.f,q6=0.f,q7=0.f;
        #pragma unroll
        for (int k = 0; k < F; k += 8) {
            int ln = k >> 3;
            q0 += __int_as_float(__builtin_amdgcn_readlane(__float_as_int(re[0]), ln)) * wcol[k + 0];
            q1 += __int_as_float(__builtin_amdgcn_readlane(__float_as_int(re[1]), ln)) * wcol[k + 1];
            q2 += __int_as_float(__builtin_amdgcn_readlane(__float_as_int(re[2]), ln)) * wcol[k + 2];
            q3 += __int_as_float(__builtin_amdgcn_readlane(__float_as_int(re[3]), ln)) * wcol[k + 3];
            q4 += __int_as_float(__builtin_amdgcn_readlane(__float_as_int(re[4]), ln)) * wcol[k + 4];
            q5 += __int_as_float(__builtin_amdgcn_readlane(__float_as_int(re[5]), ln)) * wcol[k + 5];
            q6 += __int_as_float(__builtin_amdgcn_readlane(__float_as_int(re[6]), ln)) * wcol[k + 6];
            q7 += __int_as_float(__builtin_amdgcn_readlane(__float_as_int(re[7]), ln)) * wcol[k + 7];
        }
        float hv = ((q0 + q1) + (q2 + q3)) + ((q4 + q5) + (q6 + q7)) + bgl;
        hv = hv > 0.f ? hv : 0.f;

        float p = hv * wal;
        #pragma unroll
        for (int o = 32; o > 0; o >>= 1)
            p += __shfl_down(p, o, 64);
        float s = __int_as_float(__builtin_amdgcn_readlane(__float_as_int(p), 0)) + ba0;
        float e = __expf(s);    // unshifted: softmax ratio is shift-invariant

        int g = batch[n];       // wave-uniform
        if (g != cur_g) {
            atomicAdd(&out_acc[cur_g * F + lane], accw);
            if (lane == 0) atomicAdd(&denom[cur_g], denw);
            accw = 0.f; denw = 0.f; cur_g = g;
        }
        accw += e * hv;
        denw += e;
    }
    atomicAdd(&out_acc[cur_g * F + lane], accw);
    if (lane == 0) atomicAdd(&denom[cur_g], denw);
}

// ---------- K6: out /= denom ----------
__global__ __launch_bounds__(256) void finalize_kernel(
        float* __restrict__ out, const float* __restrict__ denom) {
    int i = blockIdx.x * 256 + threadIdx.x;
    if (i >= N_GRAPHS * F) return;
    float d = denom[i >> 6];
    out[i] = (d > 0.f) ? out[i] / d : 0.f;
}

extern "C" void kernel_launch(void* const* d_in, const int* in_sizes, int n_in,
                              void* d_out, int out_size, void* d_ws, size_t ws_size,
                              hipStream_t stream) {
    const float* x     = (const float*)d_in[0];
    const int*   ei    = (const int*)d_in[1];   // [2, N_EDGES]
    const int*   batch = (const int*)d_in[2];   // [N_NODES]
    const float* Wg    = (const float*)d_in[3];
    const float* bg    = (const float*)d_in[4];
    const float* Wa    = (const float*)d_in[5];
    const float* ba    = (const float*)d_in[6];
    float* out = (float*)d_out;

    const int* src = ei;
    const int* dst = ei + N_EDGES;

    // workspace layout (bytes, 256-aligned)
    char* ws = (char*)d_ws;
    int*            cnt    = (int*)(ws);                     // 306,544
    int*            start  = (int*)(ws +   306688);          // 306,544
    int*            bbase  = (int*)(ws +   613376);          // 1,568
    unsigned int*   pairs  = (unsigned int*)(ws +  615168);  // 6,400,000
    int*            eidx   = (int*)(ws +  7015168);          // 6,400,000
    int*            noff   = (int*)(ws + 13415168);          // 400,004
    float*          denom  = (float*)(ws + 13815424);        // 1,024
    unsigned short* xh     = (unsigned short*)(ws + 13816448); // 12,800,000

    hipMemsetAsync(out,   0, (size_t)N_GRAPHS * F * sizeof(float), stream);
    hipMemsetAsync(denom, 0, N_GRAPHS * sizeof(float), stream);

    cast_kernel        <<<(N_NODES * F / 4) / 256, 256, 0, stream>>>(x, xh);
    hist_kernel        <<<NCHUNK, 1024, 0, stream>>>(dst, cnt);
    chunk_scan_kernel  <<<1, 512, 0, stream>>>(cnt, start, bbase);
    scatter_kernel     <<<NCHUNK, 1024, 0, stream>>>(src, dst, start, pairs);
    bucket_sort_kernel <<<NBUCKET, 1024, 0, stream>>>(pairs, bbase, eidx, noff);
    gather_pool_kernel <<<GT_BLOCKS, 256, 0, stream>>>(
        xh, noff, eidx, batch, Wg, bg, Wa, ba, out, denom);
    finalize_kernel    <<<(N_GRAPHS * F + 255) / 256, 256, 0, stream>>>(out, denom);
}